// Round 19
// baseline (40.948 us; speedup 1.0000x reference)
//
#include <hip/hip_runtime.h>

// Fast Tucker-Taylor forward. Round 19: r18 + K2 wave-split-K
// (512 threads; group g does K-half; LDS reduce). K1/K3 r18 verbatim.
//   K1 prep_gemmx : 512-thr; X-GEMM split-K (8 steps) + prep blocks.
//   K2 kron_fused : 512-thr; t2 8 intervals/group; t1 16 steps/group.
//   K3 gemm_y     : BM=64, BN=128.
//
// Z f16 cols: z00 0..31 | z10 32..63 | z11 64..95 | z20 96..127 | z21 128..159 | z22 160..191

typedef float f4 __attribute__((ext_vector_type(4)));
typedef _Float16 h8 __attribute__((ext_vector_type(8)));
typedef _Float16 h4 __attribute__((ext_vector_type(4)));
typedef unsigned int u32x4 __attribute__((ext_vector_type(4)));

// ws byte offsets
#define ZH_OFF  0u           // 4096*192 f16 = 1,572,864 B
#define TH_OFF  1572864u     // 4096*64 f16  =   524,288 B
#define OCH_OFF 2097152u     // 1024*96 f16  =   196,608 B
#define G2H_OFF 2293760u     // 1024*1024 f16 = 2,097,152 B (end 4,390,912)

__device__ __forceinline__ h8 splat8(unsigned int u) {
    _Float16 s = __builtin_bit_cast(_Float16, (unsigned short)(u & 0xffffu));
    return h8{ s, s, s, s, s, s, s, s };
}

// Integer-only broadcast-pair staging (r9 miscompile fix): 16 halves
// (2 x uint4) -> 16 u32 broadcast pairs.
__device__ __forceinline__ void stage_bcast16(const _Float16* zsrc, unsigned int* dst) {
    u32x4 u0 = *(const u32x4*)zsrc;
    u32x4 u1 = *(const u32x4*)(zsrc + 8);
    #pragma unroll
    for (int k = 0; k < 4; ++k) {
        dst[2*k]       = (u0[k] & 0xffffu) * 0x00010001u;
        dst[2*k + 1]   = (u0[k] >> 16)     * 0x00010001u;
        dst[8 + 2*k]   = (u1[k] & 0xffffu) * 0x00010001u;
        dst[8 + 2*k+1] = (u1[k] >> 16)     * 0x00010001u;
    }
}

// ---------------- K1: prep + X-GEMM (wave-split-K, 512 threads; r18) -------
__global__ __launch_bounds__(512) void prep_gemmx(
    const float* __restrict__ X,
    const float* __restrict__ I0, const float* __restrict__ I1, const float* __restrict__ I2,
    const float* __restrict__ O0, const float* __restrict__ O1, const float* __restrict__ O2,
    const float* __restrict__ G0, const float* __restrict__ G2,
    _Float16* __restrict__ Och, _Float16* __restrict__ G2h, _Float16* __restrict__ Z)
{
    const int bx = blockIdx.x;
    const int t = threadIdx.x;
    if (bx >= 192) {
        if (bx < 704) {            // G2 -> f16
            int i = ((bx - 192) * 512 + t) * 4;
            f4 v = *(const f4*)(G2 + i);
            h4 o = { (_Float16)v[0], (_Float16)v[1], (_Float16)v[2], (_Float16)v[3] };
            *(h4*)(G2h + i) = o;
        } else {                   // Och
            int idx = (bx - 704) * 512 + t;
            int o = idx / 96, j = idx - o * 96;
            float v;
            if (j < 32) {
                v = 0.f;
                #pragma unroll
                for (int q = 0; q < 32; ++q) v += O0[o*32 + q] * G0[q*32 + j];
            } else if (j < 64) v = O1[o*32 + (j - 32)];
            else               v = O2[o*32 + (j - 64)];
            Och[idx] = (_Float16)v;
        }
        return;
    }
    __shared__ _Float16 As[2][2][64 * 64];     // [group][buf]
    __shared__ _Float16 Bs[2][2][64 * 64];
    const int g  = t >> 8;
    const int tt = t & 255;
    const int work = (bx & 7) * 24 + (bx >> 3);       // XCD-chunked (192=8*24)
    const int m0 = (work / 3) * 64, n0 = (work % 3) * 64;
    const int wid = tt >> 6, lane = tt & 63;
    const int wr = wid >> 1, wc = wid & 1;
    const int lr = lane & 15, lg = lane >> 4;
    const int arow = tt >> 2, aq = tt & 3;

    const float* xbase = X + (size_t)(m0 + arow) * 1024 + g * 512 + aq * 16;
    const int wrow = n0 + arow;
    const float* wbase = (wrow < 32) ? I0 + (size_t)wrow * 1024
                       : (wrow < 96) ? I1 + (size_t)(wrow - 32) * 1024
                                     : I2 + (size_t)(wrow - 96) * 1024;
    wbase += g * 512 + aq * 16;
    const int sw0 = arow * 64 + (((aq * 2)     ^ (arow & 7)) << 3);
    const int sw1 = arow * 64 + (((aq * 2 + 1) ^ (arow & 7)) << 3);

    f4 xa[2][4], wa[2][4];
    #define LOADX(set, step) { \
        const float* xp = xbase + (step) * 64; \
        const float* wp = wbase + (step) * 64; \
        _Pragma("unroll") \
        for (int q = 0; q < 4; ++q) { xa[set][q] = *(const f4*)(xp + q*4); wa[set][q] = *(const f4*)(wp + q*4); } }
    #define STAGE(set, buf) { \
        h8 ha0, ha1, hb0, hb1; \
        _Pragma("unroll") \
        for (int j = 0; j < 4; ++j) { \
            ha0[j] = (_Float16)xa[set][0][j]; ha0[4+j] = (_Float16)xa[set][1][j]; \
            ha1[j] = (_Float16)xa[set][2][j]; ha1[4+j] = (_Float16)xa[set][3][j]; \
            hb0[j] = (_Float16)wa[set][0][j]; hb0[4+j] = (_Float16)wa[set][1][j]; \
            hb1[j] = (_Float16)wa[set][2][j]; hb1[4+j] = (_Float16)wa[set][3][j]; \
        } \
        *(h8*)&As[g][buf][sw0] = ha0; *(h8*)&As[g][buf][sw1] = ha1; \
        *(h8*)&Bs[g][buf][sw0] = hb0; *(h8*)&Bs[g][buf][sw1] = hb1; }

    LOADX(0, 0); LOADX(1, 1);
    STAGE(0, 0);
    LOADX(0, 2);

    f4 acc[2][2];
    #pragma unroll
    for (int mt = 0; mt < 2; ++mt)
        #pragma unroll
        for (int nt = 0; nt < 2; ++nt) acc[mt][nt] = f4{0.f,0.f,0.f,0.f};

    #pragma unroll
    for (int s = 0; s < 8; ++s) {
        const int cur = s & 1;
        __syncthreads();
        if (s < 7) STAGE((s + 1) & 1, cur ^ 1);
        if (s < 5) LOADX((s + 1) & 1, s + 3);
        #pragma unroll
        for (int ks = 0; ks < 2; ++ks) {
            h8 av[2], bv[2];
            #pragma unroll
            for (int mt = 0; mt < 2; ++mt) {
                int row = wr * 32 + mt * 16 + lr, gg = ks * 4 + lg;
                av[mt] = *(const h8*)&As[g][cur][row * 64 + ((gg ^ (row & 7)) << 3)];
            }
            #pragma unroll
            for (int nt = 0; nt < 2; ++nt) {
                int row = wc * 32 + nt * 16 + lr, gg = ks * 4 + lg;
                bv[nt] = *(const h8*)&Bs[g][cur][row * 64 + ((gg ^ (row & 7)) << 3)];
            }
            #pragma unroll
            for (int mt = 0; mt < 2; ++mt)
                #pragma unroll
                for (int nt = 0; nt < 2; ++nt)
                    acc[mt][nt] = __builtin_amdgcn_mfma_f32_16x16x32_f16(av[mt], bv[nt], acc[mt][nt], 0, 0, 0);
        }
    }
    #undef LOADX
    #undef STAGE
    __syncthreads();
    float* Red = (float*)&As[0][0][0];
    if (g == 1) {
        #pragma unroll
        for (int mt = 0; mt < 2; ++mt)
            #pragma unroll
            for (int nt = 0; nt < 2; ++nt)
                #pragma unroll
                for (int i = 0; i < 4; ++i)
                    Red[tt * 16 + mt * 8 + nt * 4 + i] = acc[mt][nt][i];
    }
    __syncthreads();
    if (g == 0) {
        #pragma unroll
        for (int mt = 0; mt < 2; ++mt)
            #pragma unroll
            for (int nt = 0; nt < 2; ++nt)
                #pragma unroll
                for (int i = 0; i < 4; ++i)
                    Z[(size_t)(m0 + wr*32 + mt*16 + lg*4 + i) * 192 + n0 + wc*32 + nt*16 + lr]
                        = (_Float16)(acc[mt][nt][i] + Red[tt * 16 + mt * 8 + nt * 4 + i]);
    }
}

// ---------------- K2: fused kron t2 + t1 (wave-split-K, 512 threads) -------
// t2 (bx<512): n0=(bx&15)*64, m0=(bx>>4)*128. Group g covers slices
//   16g..16g+15 as 8 barrier intervals; per-group dbuf B; zu-prefetch;
//   LDS reduce; fused z22 epilogue.
// t1 (bx>=512): m0=(bx-512)*128. Group g covers slices 16g..16g+15 (16
//   steps); per-group dbuf; LDS reduce; direct T store.
__global__ __launch_bounds__(512) void kron_fused(
    const _Float16* __restrict__ Z, const _Float16* __restrict__ G2h,
    const float* __restrict__ G1, _Float16* __restrict__ T)
{
    __shared__ __align__(16) unsigned char smem[57856];
    unsigned int* Zs1 = (unsigned int*)smem;               // [128][33] = 16896 B
    _Float16* Bs = (_Float16*)(smem + 16896);              // t2: [g][buf][2][64][40]; t1: [g][buf][32][40]
    const int bx = blockIdx.x;
    const int t = threadIdx.x;
    const int g = t >> 8, tt = t & 255;
    const int wid = tt >> 6, lane = tt & 63;
    const int lr = lane & 15, lg = lane >> 4;
    const bool is_t2 = bx < 512;
    const int m0 = is_t2 ? (bx >> 4) * 128 : (bx - 512) * 128;
    const int zcol = is_t2 ? 128 : 64;                     // z21 vs z11

    if (t < 256) {   // outer z factor -> broadcast u32 pairs (integer-only)
        int row = t >> 1, c0 = (t & 1) * 16;
        stage_bcast16(Z + (size_t)(m0 + row) * 192 + zcol + c0, Zs1 + row * 33 + c0);
    }

    if (is_t2) {
        const int n0 = (bx & 15) * 64;
        const int wm0 = (wid >> 1) * 64, wn0 = (wid & 1) * 32;
        h8 a0v[4];
        #pragma unroll
        for (int mt = 0; mt < 4; ++mt)
            a0v[mt] = *(const h8*)(Z + (size_t)(m0 + wm0 + mt*16 + lr) * 192 + 96 + lg * 8);

        f4 acc[4][2];
        #pragma unroll
        for (int mt = 0; mt < 4; ++mt)
            #pragma unroll
            for (int nt = 0; nt < 2; ++nt) acc[mt][nt] = f4{0.f, 0.f, 0.f, 0.f};

        const int brow = tt >> 2, bg = tt & 3;
        const f4* gsrc = (const f4*)(G2h + (size_t)(n0 + brow) * 1024 + g * 512 + bg * 8);
        _Float16* BsG = Bs + g * 10240;          // per-group: 2 bufs x 5120 f16
        // local interval i covers slices 16g+2i, 16g+2i+1 -> gsrc[8i], gsrc[8i+4]
        f4 brA[2], brB[2];
        brA[0] = gsrc[0];  brB[0] = gsrc[4];     // interval 0
        {
            *(f4*)&BsG[0 * 5120 + 0 * 2560 + brow * 40 + bg * 8] = brA[0];
            *(f4*)&BsG[0 * 5120 + 1 * 2560 + brow * 40 + bg * 8] = brB[0];
        }
        brA[1] = gsrc[8];  brB[1] = gsrc[12];    // interval 1
        brA[0] = gsrc[16]; brB[0] = gsrc[20];    // interval 2

        unsigned int zu[2][2][4];                // [set][q][mt] Zs1 prefetch
        #pragma unroll
        for (int i = 0; i < 8; ++i) {
            const int cur = i & 1;
            __syncthreads();
            if (i == 0) {
                #pragma unroll
                for (int q = 0; q < 2; ++q)
                    #pragma unroll
                    for (int mt = 0; mt < 4; ++mt)
                        zu[0][q][mt] = Zs1[(wm0 + mt*16 + lr) * 33 + 16*g + q];
            }
            if (i < 7) {
                const int set = (i + 1) & 1;
                *(f4*)&BsG[(cur ^ 1) * 5120 + 0 * 2560 + brow * 40 + bg * 8] = brA[set];
                *(f4*)&BsG[(cur ^ 1) * 5120 + 1 * 2560 + brow * 40 + bg * 8] = brB[set];
                #pragma unroll
                for (int q = 0; q < 2; ++q)
                    #pragma unroll
                    for (int mt = 0; mt < 4; ++mt)
                        zu[set][q][mt] = Zs1[(wm0 + mt*16 + lr) * 33 + 16*g + 2*(i+1) + q];
            }
            if (i < 5) {
                const int set = (i + 1) & 1;
                brA[set] = gsrc[(i + 3) * 8];
                brB[set] = gsrc[(i + 3) * 8 + 4];
            }
            #pragma unroll
            for (int q = 0; q < 2; ++q) {
                h8 bf0 = *(const h8*)&BsG[cur * 5120 + q * 2560 + (wn0 + lr) * 40 + lg * 8];
                h8 bf1 = *(const h8*)&BsG[cur * 5120 + q * 2560 + (wn0 + 16 + lr) * 40 + lg * 8];
                #pragma unroll
                for (int mt = 0; mt < 4; ++mt) {
                    h8 z1b = splat8(zu[cur][q][mt]);
                    h8 af = z1b * a0v[mt];
                    acc[mt][0] = __builtin_amdgcn_mfma_f32_16x16x32_f16(af, bf0, acc[mt][0], 0, 0, 0);
                    acc[mt][1] = __builtin_amdgcn_mfma_f32_16x16x32_f16(af, bf1, acc[mt][1], 0, 0, 0);
                }
            }
        }

        // ---- cross-group reduction (Red at smem+16896, 32 KB) ----
        __syncthreads();
        float* Red = (float*)(smem + 16896);
        if (g == 1) {
            #pragma unroll
            for (int mt = 0; mt < 4; ++mt)
                #pragma unroll
                for (int nt = 0; nt < 2; ++nt)
                    #pragma unroll
                    for (int i = 0; i < 4; ++i)
                        Red[tt * 32 + (mt * 2 + nt) * 4 + i] = acc[mt][nt][i];
        }
        __syncthreads();
        if (g == 0) {
            #pragma unroll
            for (int mt = 0; mt < 4; ++mt)
                #pragma unroll
                for (int nt = 0; nt < 2; ++nt)
                    #pragma unroll
                    for (int i = 0; i < 4; ++i)
                        acc[mt][nt][i] += Red[tt * 32 + (mt * 2 + nt) * 4 + i];
        }
        __syncthreads();                          // Red reads done before Ms overwrite
        float* Ms = (float*)smem;                 // [128][66]
        if (g == 0) {
            #pragma unroll
            for (int mt = 0; mt < 4; ++mt)
                #pragma unroll
                for (int nt = 0; nt < 2; ++nt)
                    #pragma unroll
                    for (int i = 0; i < 4; ++i)
                        Ms[(wm0 + mt*16 + lg*4 + i) * 66 + wn0 + nt*16 + lr] = acc[mt][nt][i];
        }
        __syncthreads();
        if (t < 256) {
            int row = t >> 1, rl = t & 1;
            const _Float16* z2p = Z + (size_t)(m0 + row) * 192 + 160;
            const float* mrow = Ms + row * 66 + rl * 32;
            float sum = 0.f;
            #pragma unroll
            for (int r2 = 0; r2 < 32; ++r2) sum += mrow[r2] * (float)z2p[r2];
            T[(size_t)(m0 + row) * 64 + 32 + (bx & 15) * 2 + rl] = (_Float16)sum;
        }
    } else {
        // ---- t1: kron(z11,z10) @ G1^T, split-K across groups ----
        h8 a0v[2];
        #pragma unroll
        for (int mt = 0; mt < 2; ++mt)
            a0v[mt] = *(const h8*)(Z + (size_t)(m0 + wid*32 + mt*16 + lr) * 192 + 32 + lg * 8);

        const int brow = tt >> 3, bq = (tt & 7) * 4;
        const float* g1src = G1 + (size_t)brow * 1024 + g * 512 + bq;
        _Float16* BsG = Bs + g * 2560;            // per-group: 2 bufs x 1280 f16
        f4 bw = *(const f4*)g1src;
        {
            h4 bh = { (_Float16)bw[0], (_Float16)bw[1], (_Float16)bw[2], (_Float16)bw[3] };
            *(h4*)&BsG[brow * 40 + bq] = bh;
        }
        bw = *(const f4*)(g1src + 32);

        f4 acc[2][2];
        #pragma unroll
        for (int mt = 0; mt < 2; ++mt)
            #pragma unroll
            for (int nt = 0; nt < 2; ++nt) acc[mt][nt] = f4{0.f,0.f,0.f,0.f};
        __syncthreads();

        for (int s = 0; s < 16; ++s) {
            const int cur = s & 1;
            if (s < 15) {
                h4 bh = { (_Float16)bw[0], (_Float16)bw[1], (_Float16)bw[2], (_Float16)bw[3] };
                *(h4*)&BsG[(cur ^ 1) * 1280 + brow * 40 + bq] = bh;
            }
            if (s < 14) bw = *(const f4*)(g1src + (s + 2) * 32);
            h8 bf[2];
            #pragma unroll
            for (int nt = 0; nt < 2; ++nt)
                bf[nt] = *(const h8*)&BsG[cur * 1280 + (nt*16 + lr) * 40 + lg * 8];
            #pragma unroll
            for (int mt = 0; mt < 2; ++mt) {
                h8 z1b = splat8(Zs1[(wid*32 + mt*16 + lr) * 33 + 16*g + s]);
                h8 af = z1b * a0v[mt];
                acc[mt][0] = __builtin_amdgcn_mfma_f32_16x16x32_f16(af, bf[0], acc[mt][0], 0, 0, 0);
                acc[mt][1] = __builtin_amdgcn_mfma_f32_16x16x32_f16(af, bf[1], acc[mt][1], 0, 0, 0);
            }
            __syncthreads();
        }
        // ---- cross-group reduction (Red reuses dead Zs1 region, 16 KB) ----
        float* Red = (float*)smem;
        if (g == 1) {
            #pragma unroll
            for (int mt = 0; mt < 2; ++mt)
                #pragma unroll
                for (int nt = 0; nt < 2; ++nt)
                    #pragma unroll
                    for (int i = 0; i < 4; ++i)
                        Red[tt * 16 + (mt * 2 + nt) * 4 + i] = acc[mt][nt][i];
        }
        __syncthreads();
        if (g == 0) {
            #pragma unroll
            for (int mt = 0; mt < 2; ++mt)
                #pragma unroll
                for (int nt = 0; nt < 2; ++nt)
                    #pragma unroll
                    for (int i = 0; i < 4; ++i)
                        T[(size_t)(m0 + wid*32 + mt*16 + lg*4 + i) * 64 + nt*16 + lr]
                            = (_Float16)(acc[mt][nt][i] + Red[tt * 16 + (mt * 2 + nt) * 4 + i]);
        }
    }
}

// ---------------- K3: Y = const + [z00|T] @ Och^T  (BM=64, BN=128; r11) ----------------
__global__ __launch_bounds__(256) void gemm_y_mfma(
    const _Float16* __restrict__ Z, const _Float16* __restrict__ T,
    const _Float16* __restrict__ Och, const float* __restrict__ cst,
    float* __restrict__ Y)
{
    __shared__ _Float16 As[64 * 104];
    __shared__ _Float16 Bs[128 * 104];
    const int t = threadIdx.x;
    const int n0 = blockIdx.x * 128, m0 = blockIdx.y * 64;
    {   // A: 64 rows x 96 = [z00 | T]; 4 threads/row, 24 halves each
        int row = t >> 2, seg = t & 3;
        const _Float16* zp = Z + (size_t)(m0 + row) * 192;
        const _Float16* tp = T + (size_t)(m0 + row) * 64;
        _Float16* dst = As + row * 104;
        if (seg == 0) {
            *(h8*)(dst)      = *(const h8*)(zp);
            *(h8*)(dst + 8)  = *(const h8*)(zp + 8);
            *(h8*)(dst + 16) = *(const h8*)(zp + 16);
        } else if (seg == 1) {
            *(h8*)(dst + 24) = *(const h8*)(zp + 24);
            *(h8*)(dst + 32) = *(const h8*)(tp);
            *(h8*)(dst + 40) = *(const h8*)(tp + 8);
        } else if (seg == 2) {
            *(h8*)(dst + 48) = *(const h8*)(tp + 16);
            *(h8*)(dst + 56) = *(const h8*)(tp + 24);
            *(h8*)(dst + 64) = *(const h8*)(tp + 32);
        } else {
            *(h8*)(dst + 72) = *(const h8*)(tp + 40);
            *(h8*)(dst + 80) = *(const h8*)(tp + 48);
            *(h8*)(dst + 88) = *(const h8*)(tp + 56);
        }
        // B: 128 rows x 96 Och
        int row2 = t >> 1, half = t & 1;
        const _Float16* src = Och + (size_t)(n0 + row2) * 96 + half * 48;
        _Float16* bdst = Bs + row2 * 104 + half * 48;
        #pragma unroll
        for (int q = 0; q < 6; ++q) *(h8*)(bdst + q * 8) = *(const h8*)(src + q * 8);
    }
    const int wid = t >> 6, lane = t & 63;
    const int wvr = wid >> 1, wvc = wid & 1;   // 2 m-waves x 2 n-waves
    const int lr = lane & 15, lg = lane >> 4;
    float bias[4];
    #pragma unroll
    for (int nt = 0; nt < 4; ++nt) bias[nt] = cst[n0 + wvc*64 + nt*16 + lr];
    __syncthreads();

    f4 acc[2][4];
    #pragma unroll
    for (int mt = 0; mt < 2; ++mt)
        #pragma unroll
        for (int nt = 0; nt < 4; ++nt) acc[mt][nt] = f4{0.f,0.f,0.f,0.f};

    #pragma unroll
    for (int ks = 0; ks < 3; ++ks) {
        h8 av[2], bv[4];
        #pragma unroll
        for (int mt = 0; mt < 2; ++mt)
            av[mt] = *(const h8*)&As[(wvr*32 + mt*16 + lr) * 104 + ks*32 + lg*8];
        #pragma unroll
        for (int nt = 0; nt < 4; ++nt)
            bv[nt] = *(const h8*)&Bs[(wvc*64 + nt*16 + lr) * 104 + ks*32 + lg*8];
        #pragma unroll
        for (int mt = 0; mt < 2; ++mt)
            #pragma unroll
            for (int nt = 0; nt < 4; ++nt)
                acc[mt][nt] = __builtin_amdgcn_mfma_f32_16x16x32_f16(av[mt], bv[nt], acc[mt][nt], 0, 0, 0);
    }
    #pragma unroll
    for (int mt = 0; mt < 2; ++mt)
        #pragma unroll
        for (int nt = 0; nt < 4; ++nt)
            #pragma unroll
            for (int i = 0; i < 4; ++i)
                Y[(size_t)(m0 + wvr*32 + mt*16 + lg*4 + i) * 1024 + n0 + wvc*64 + nt*16 + lr]
                    = acc[mt][nt][i] + bias[nt];
}

extern "C" void kernel_launch(void* const* d_in, const int* in_sizes, int n_in,
                              void* d_out, int out_size, void* d_ws, size_t ws_size,
                              hipStream_t stream) {
    const float* X   = (const float*)d_in[0];
    const float* cst = (const float*)d_in[1];
    const float* O0  = (const float*)d_in[2];
    const float* I0  = (const float*)d_in[3];
    const float* G0  = (const float*)d_in[4];
    const float* O1  = (const float*)d_in[5];
    const float* I1  = (const float*)d_in[6];
    const float* G1  = (const float*)d_in[7];
    const float* O2  = (const float*)d_in[8];
    const float* I2  = (const float*)d_in[9];
    const float* G2  = (const float*)d_in[10];
    unsigned char* ws = (unsigned char*)d_ws;
    _Float16* Zh  = (_Float16*)(ws + ZH_OFF);
    _Float16* Th  = (_Float16*)(ws + TH_OFF);
    _Float16* Oh  = (_Float16*)(ws + OCH_OFF);
    _Float16* G2h = (_Float16*)(ws + G2H_OFF);
    float* Y = (float*)d_out;

    prep_gemmx<<<896, 512, 0, stream>>>(X, I0, I1, I2, O0, O1, O2, G0, G2, Oh, G2h, Zh);
    kron_fused<<<544, 512, 0, stream>>>(Zh, G2h, G1, Th);
    gemm_y_mfma<<<dim3(8, 64), 256, 0, stream>>>(Zh, Th, Oh, cst, Y);
}

// Round 20
// 36.494 us; speedup vs baseline: 1.1221x; 1.1221x over previous
//
#include <hip/hip_runtime.h>

// Fast Tucker-Taylor forward. Round 20: revert to r18 (best measured:
// 36.5us). r19's K2 wave-split-K regressed (duplicated B-staging LDS
// traffic, 8-wave barriers) and is dropped.
//   K1 prep_gemmx : 512-thr; X-GEMM wave-split-K (8 steps) + prep blocks.
//   K2 kron_fused : 256-thr; t2 BM=128,BN=64, Q=2, 16 barriers, zu-prefetch.
//   K3 gemm_y     : BM=64, BN=128.
//
// Z f16 cols: z00 0..31 | z10 32..63 | z11 64..95 | z20 96..127 | z21 128..159 | z22 160..191

typedef float f4 __attribute__((ext_vector_type(4)));
typedef _Float16 h8 __attribute__((ext_vector_type(8)));
typedef _Float16 h4 __attribute__((ext_vector_type(4)));
typedef unsigned int u32x4 __attribute__((ext_vector_type(4)));

// ws byte offsets
#define ZH_OFF  0u           // 4096*192 f16 = 1,572,864 B
#define TH_OFF  1572864u     // 4096*64 f16  =   524,288 B
#define OCH_OFF 2097152u     // 1024*96 f16  =   196,608 B
#define G2H_OFF 2293760u     // 1024*1024 f16 = 2,097,152 B (end 4,390,912)

__device__ __forceinline__ h8 splat8(unsigned int u) {
    _Float16 s = __builtin_bit_cast(_Float16, (unsigned short)(u & 0xffffu));
    return h8{ s, s, s, s, s, s, s, s };
}

// Integer-only broadcast-pair staging (r9 miscompile fix): 16 halves
// (2 x uint4) -> 16 u32 broadcast pairs.
__device__ __forceinline__ void stage_bcast16(const _Float16* zsrc, unsigned int* dst) {
    u32x4 u0 = *(const u32x4*)zsrc;
    u32x4 u1 = *(const u32x4*)(zsrc + 8);
    #pragma unroll
    for (int k = 0; k < 4; ++k) {
        dst[2*k]       = (u0[k] & 0xffffu) * 0x00010001u;
        dst[2*k + 1]   = (u0[k] >> 16)     * 0x00010001u;
        dst[8 + 2*k]   = (u1[k] & 0xffffu) * 0x00010001u;
        dst[8 + 2*k+1] = (u1[k] >> 16)     * 0x00010001u;
    }
}

// ---------------- K1: prep + X-GEMM (wave-split-K, 512 threads) ------------
__global__ __launch_bounds__(512) void prep_gemmx(
    const float* __restrict__ X,
    const float* __restrict__ I0, const float* __restrict__ I1, const float* __restrict__ I2,
    const float* __restrict__ O0, const float* __restrict__ O1, const float* __restrict__ O2,
    const float* __restrict__ G0, const float* __restrict__ G2,
    _Float16* __restrict__ Och, _Float16* __restrict__ G2h, _Float16* __restrict__ Z)
{
    const int bx = blockIdx.x;
    const int t = threadIdx.x;
    if (bx >= 192) {
        if (bx < 704) {            // G2 -> f16 (512 blocks x 512 thr x 4)
            int i = ((bx - 192) * 512 + t) * 4;
            f4 v = *(const f4*)(G2 + i);
            h4 o = { (_Float16)v[0], (_Float16)v[1], (_Float16)v[2], (_Float16)v[3] };
            *(h4*)(G2h + i) = o;
        } else {                   // Och (192 blocks x 512 thr)
            int idx = (bx - 704) * 512 + t;
            int o = idx / 96, j = idx - o * 96;
            float v;
            if (j < 32) {
                v = 0.f;
                #pragma unroll
                for (int q = 0; q < 32; ++q) v += O0[o*32 + q] * G0[q*32 + j];
            } else if (j < 64) v = O1[o*32 + (j - 32)];
            else               v = O2[o*32 + (j - 64)];
            Och[idx] = (_Float16)v;
        }
        return;
    }
    // ---- X-GEMM: wave-split-K. group g = K-half; 8 steps; LDS dbuf. ----
    __shared__ _Float16 As[2][2][64 * 64];     // [group][buf]
    __shared__ _Float16 Bs[2][2][64 * 64];
    const int g  = t >> 8;                     // 0 or 1
    const int tt = t & 255;
    const int work = (bx & 7) * 24 + (bx >> 3);       // XCD-chunked (192=8*24)
    const int m0 = (work / 3) * 64, n0 = (work % 3) * 64;
    const int wid = tt >> 6, lane = tt & 63;
    const int wr = wid >> 1, wc = wid & 1;
    const int lr = lane & 15, lg = lane >> 4;
    const int arow = tt >> 2, aq = tt & 3;

    const float* xbase = X + (size_t)(m0 + arow) * 1024 + g * 512 + aq * 16;
    const int wrow = n0 + arow;
    const float* wbase = (wrow < 32) ? I0 + (size_t)wrow * 1024
                       : (wrow < 96) ? I1 + (size_t)(wrow - 32) * 1024
                                     : I2 + (size_t)(wrow - 96) * 1024;
    wbase += g * 512 + aq * 16;
    const int sw0 = arow * 64 + (((aq * 2)     ^ (arow & 7)) << 3);
    const int sw1 = arow * 64 + (((aq * 2 + 1) ^ (arow & 7)) << 3);

    f4 xa[2][4], wa[2][4];
    #define LOADX(set, step) { \
        const float* xp = xbase + (step) * 64; \
        const float* wp = wbase + (step) * 64; \
        _Pragma("unroll") \
        for (int q = 0; q < 4; ++q) { xa[set][q] = *(const f4*)(xp + q*4); wa[set][q] = *(const f4*)(wp + q*4); } }
    #define STAGE(set, buf) { \
        h8 ha0, ha1, hb0, hb1; \
        _Pragma("unroll") \
        for (int j = 0; j < 4; ++j) { \
            ha0[j] = (_Float16)xa[set][0][j]; ha0[4+j] = (_Float16)xa[set][1][j]; \
            ha1[j] = (_Float16)xa[set][2][j]; ha1[4+j] = (_Float16)xa[set][3][j]; \
            hb0[j] = (_Float16)wa[set][0][j]; hb0[4+j] = (_Float16)wa[set][1][j]; \
            hb1[j] = (_Float16)wa[set][2][j]; hb1[4+j] = (_Float16)wa[set][3][j]; \
        } \
        *(h8*)&As[g][buf][sw0] = ha0; *(h8*)&As[g][buf][sw1] = ha1; \
        *(h8*)&Bs[g][buf][sw0] = hb0; *(h8*)&Bs[g][buf][sw1] = hb1; }

    LOADX(0, 0); LOADX(1, 1);
    STAGE(0, 0);
    LOADX(0, 2);

    f4 acc[2][2];
    #pragma unroll
    for (int mt = 0; mt < 2; ++mt)
        #pragma unroll
        for (int nt = 0; nt < 2; ++nt) acc[mt][nt] = f4{0.f,0.f,0.f,0.f};

    #pragma unroll
    for (int s = 0; s < 8; ++s) {
        const int cur = s & 1;
        __syncthreads();
        if (s < 7) STAGE((s + 1) & 1, cur ^ 1);
        if (s < 5) LOADX((s + 1) & 1, s + 3);
        #pragma unroll
        for (int ks = 0; ks < 2; ++ks) {
            h8 av[2], bv[2];
            #pragma unroll
            for (int mt = 0; mt < 2; ++mt) {
                int row = wr * 32 + mt * 16 + lr, gg = ks * 4 + lg;
                av[mt] = *(const h8*)&As[g][cur][row * 64 + ((gg ^ (row & 7)) << 3)];
            }
            #pragma unroll
            for (int nt = 0; nt < 2; ++nt) {
                int row = wc * 32 + nt * 16 + lr, gg = ks * 4 + lg;
                bv[nt] = *(const h8*)&Bs[g][cur][row * 64 + ((gg ^ (row & 7)) << 3)];
            }
            #pragma unroll
            for (int mt = 0; mt < 2; ++mt)
                #pragma unroll
                for (int nt = 0; nt < 2; ++nt)
                    acc[mt][nt] = __builtin_amdgcn_mfma_f32_16x16x32_f16(av[mt], bv[nt], acc[mt][nt], 0, 0, 0);
        }
    }
    #undef LOADX
    #undef STAGE
    // ---- reduce the two K-halves via LDS (16 KB, reuses dead tiles) ----
    __syncthreads();
    float* Red = (float*)&As[0][0][0];
    if (g == 1) {
        #pragma unroll
        for (int mt = 0; mt < 2; ++mt)
            #pragma unroll
            for (int nt = 0; nt < 2; ++nt)
                #pragma unroll
                for (int i = 0; i < 4; ++i)
                    Red[tt * 16 + mt * 8 + nt * 4 + i] = acc[mt][nt][i];
    }
    __syncthreads();
    if (g == 0) {
        #pragma unroll
        for (int mt = 0; mt < 2; ++mt)
            #pragma unroll
            for (int nt = 0; nt < 2; ++nt)
                #pragma unroll
                for (int i = 0; i < 4; ++i)
                    Z[(size_t)(m0 + wr*32 + mt*16 + lg*4 + i) * 192 + n0 + wc*32 + nt*16 + lr]
                        = (_Float16)(acc[mt][nt][i] + Red[tt * 16 + mt * 8 + nt * 4 + i]);
    }
}

// ---------------- K2: fused kron t2 + t1 (r17 structure, 256 threads) ------
__global__ __launch_bounds__(256) void kron_fused(
    const _Float16* __restrict__ Z, const _Float16* __restrict__ G2h,
    const float* __restrict__ G1, _Float16* __restrict__ T)
{
    __shared__ __align__(16) unsigned char smem[37376];
    unsigned int* Zs1 = (unsigned int*)smem;               // [128][33]
    _Float16* Bs = (_Float16*)(smem + 16896);              // t2: [2][2][64][40]; t1: [2][32][40]
    const int bx = blockIdx.x;
    const int t = threadIdx.x;
    const int wid = t >> 6, lane = t & 63;
    const int lr = lane & 15, lg = lane >> 4;
    const bool is_t2 = bx < 512;
    const int m0 = is_t2 ? (bx >> 4) * 128 : (bx - 512) * 128;
    const int zcol = is_t2 ? 128 : 64;                     // z21 vs z11

    {   // outer z factor -> broadcast u32 pairs (integer-only)
        int row = t >> 1, c0 = (t & 1) * 16;
        stage_bcast16(Z + (size_t)(m0 + row) * 192 + zcol + c0, Zs1 + row * 33 + c0);
    }

    if (is_t2) {
        const int n0 = (bx & 15) * 64;
        const int wm0 = (wid >> 1) * 64, wn0 = (wid & 1) * 32;
        h8 a0v[4];
        #pragma unroll
        for (int mt = 0; mt < 4; ++mt)
            a0v[mt] = *(const h8*)(Z + (size_t)(m0 + wm0 + mt*16 + lr) * 192 + 96 + lg * 8);

        f4 acc[4][2];
        #pragma unroll
        for (int mt = 0; mt < 4; ++mt)
            #pragma unroll
            for (int nt = 0; nt < 2; ++nt) acc[mt][nt] = f4{0.f, 0.f, 0.f, 0.f};

        const int brow = t >> 2, bg = t & 3;
        const f4* gsrc = (const f4*)(G2h + (size_t)(n0 + brow) * 1024 + bg * 8);
        f4 brA[2], brB[2];
        brA[0] = gsrc[0];  brB[0] = gsrc[4];     // interval 0
        {
            *(f4*)&Bs[0 * 5120 + 0 * 2560 + brow * 40 + bg * 8] = brA[0];
            *(f4*)&Bs[0 * 5120 + 1 * 2560 + brow * 40 + bg * 8] = brB[0];
        }
        brA[1] = gsrc[8];  brB[1] = gsrc[12];    // interval 1
        brA[0] = gsrc[16]; brB[0] = gsrc[20];    // interval 2

        unsigned int zu[2][2][4];                // [set][q][mt] Zs1 prefetch
        #pragma unroll
        for (int i = 0; i < 16; ++i) {
            const int cur = i & 1;
            __syncthreads();
            if (i == 0) {
                #pragma unroll
                for (int q = 0; q < 2; ++q)
                    #pragma unroll
                    for (int mt = 0; mt < 4; ++mt)
                        zu[0][q][mt] = Zs1[(wm0 + mt*16 + lr) * 33 + q];
            }
            if (i < 15) {
                const int set = (i + 1) & 1;
                *(f4*)&Bs[(cur ^ 1) * 5120 + 0 * 2560 + brow * 40 + bg * 8] = brA[set];
                *(f4*)&Bs[(cur ^ 1) * 5120 + 1 * 2560 + brow * 40 + bg * 8] = brB[set];
                #pragma unroll
                for (int q = 0; q < 2; ++q)
                    #pragma unroll
                    for (int mt = 0; mt < 4; ++mt)
                        zu[set][q][mt] = Zs1[(wm0 + mt*16 + lr) * 33 + 2*(i+1) + q];
            }
            if (i < 13) {
                const int set = (i + 1) & 1;
                brA[set] = gsrc[(i + 3) * 8];
                brB[set] = gsrc[(i + 3) * 8 + 4];
            }
            #pragma unroll
            for (int q = 0; q < 2; ++q) {
                h8 bf0 = *(const h8*)&Bs[cur * 5120 + q * 2560 + (wn0 + lr) * 40 + lg * 8];
                h8 bf1 = *(const h8*)&Bs[cur * 5120 + q * 2560 + (wn0 + 16 + lr) * 40 + lg * 8];
                #pragma unroll
                for (int mt = 0; mt < 4; ++mt) {
                    h8 z1b = splat8(zu[cur][q][mt]);
                    h8 af = z1b * a0v[mt];
                    acc[mt][0] = __builtin_amdgcn_mfma_f32_16x16x32_f16(af, bf0, acc[mt][0], 0, 0, 0);
                    acc[mt][1] = __builtin_amdgcn_mfma_f32_16x16x32_f16(af, bf1, acc[mt][1], 0, 0, 0);
                }
            }
        }

        __syncthreads();
        float* Ms = (float*)smem;                          // [128][66]
        #pragma unroll
        for (int mt = 0; mt < 4; ++mt)
            #pragma unroll
            for (int nt = 0; nt < 2; ++nt)
                #pragma unroll
                for (int i = 0; i < 4; ++i)
                    Ms[(wm0 + mt*16 + lg*4 + i) * 66 + wn0 + nt*16 + lr] = acc[mt][nt][i];
        __syncthreads();
        {
            int row = t >> 1, rl = t & 1;
            const _Float16* z2p = Z + (size_t)(m0 + row) * 192 + 160;
            const float* mrow = Ms + row * 66 + rl * 32;
            float sum = 0.f;
            #pragma unroll
            for (int r2 = 0; r2 < 32; ++r2) sum += mrow[r2] * (float)z2p[r2];
            T[(size_t)(m0 + row) * 64 + 32 + (bx & 15) * 2 + rl] = (_Float16)sum;
        }
    } else {
        // ---- t1: kron(z11,z10) @ G1^T (r11 verbatim) ----
        h8 a0v[2];
        #pragma unroll
        for (int mt = 0; mt < 2; ++mt)
            a0v[mt] = *(const h8*)(Z + (size_t)(m0 + wid*32 + mt*16 + lr) * 192 + 32 + lg * 8);

        const int brow = t >> 3, bq = (t & 7) * 4;
        const float* g1src = G1 + (size_t)brow * 1024 + bq;
        f4 bw = *(const f4*)g1src;
        {
            h4 bh = { (_Float16)bw[0], (_Float16)bw[1], (_Float16)bw[2], (_Float16)bw[3] };
            *(h4*)&Bs[brow * 40 + bq] = bh;
        }
        bw = *(const f4*)(g1src + 32);

        f4 acc[2][2];
        #pragma unroll
        for (int mt = 0; mt < 2; ++mt)
            #pragma unroll
            for (int nt = 0; nt < 2; ++nt) acc[mt][nt] = f4{0.f,0.f,0.f,0.f};
        __syncthreads();

        for (int s = 0; s < 32; ++s) {
            const int cur = s & 1;
            if (s < 31) {
                h4 bh = { (_Float16)bw[0], (_Float16)bw[1], (_Float16)bw[2], (_Float16)bw[3] };
                *(h4*)&Bs[(cur ^ 1) * 1280 + brow * 40 + bq] = bh;
            }
            if (s < 30) bw = *(const f4*)(g1src + (s + 2) * 32);
            h8 bf[2];
            #pragma unroll
            for (int nt = 0; nt < 2; ++nt)
                bf[nt] = *(const h8*)&Bs[cur * 1280 + (nt*16 + lr) * 40 + lg * 8];
            #pragma unroll
            for (int mt = 0; mt < 2; ++mt) {
                h8 z1b = splat8(Zs1[(wid*32 + mt*16 + lr) * 33 + s]);
                h8 af = z1b * a0v[mt];
                acc[mt][0] = __builtin_amdgcn_mfma_f32_16x16x32_f16(af, bf[0], acc[mt][0], 0, 0, 0);
                acc[mt][1] = __builtin_amdgcn_mfma_f32_16x16x32_f16(af, bf[1], acc[mt][1], 0, 0, 0);
            }
            __syncthreads();
        }
        #pragma unroll
        for (int mt = 0; mt < 2; ++mt)
            #pragma unroll
            for (int nt = 0; nt < 2; ++nt)
                #pragma unroll
                for (int i = 0; i < 4; ++i)
                    T[(size_t)(m0 + wid*32 + mt*16 + lg*4 + i) * 64 + nt*16 + lr]
                        = (_Float16)acc[mt][nt][i];
    }
}

// ---------------- K3: Y = const + [z00|T] @ Och^T  (BM=64, BN=128; r11) ----------------
__global__ __launch_bounds__(256) void gemm_y_mfma(
    const _Float16* __restrict__ Z, const _Float16* __restrict__ T,
    const _Float16* __restrict__ Och, const float* __restrict__ cst,
    float* __restrict__ Y)
{
    __shared__ _Float16 As[64 * 104];
    __shared__ _Float16 Bs[128 * 104];
    const int t = threadIdx.x;
    const int n0 = blockIdx.x * 128, m0 = blockIdx.y * 64;
    {   // A: 64 rows x 96 = [z00 | T]; 4 threads/row, 24 halves each
        int row = t >> 2, seg = t & 3;
        const _Float16* zp = Z + (size_t)(m0 + row) * 192;
        const _Float16* tp = T + (size_t)(m0 + row) * 64;
        _Float16* dst = As + row * 104;
        if (seg == 0) {
            *(h8*)(dst)      = *(const h8*)(zp);
            *(h8*)(dst + 8)  = *(const h8*)(zp + 8);
            *(h8*)(dst + 16) = *(const h8*)(zp + 16);
        } else if (seg == 1) {
            *(h8*)(dst + 24) = *(const h8*)(zp + 24);
            *(h8*)(dst + 32) = *(const h8*)(tp);
            *(h8*)(dst + 40) = *(const h8*)(tp + 8);
        } else if (seg == 2) {
            *(h8*)(dst + 48) = *(const h8*)(tp + 16);
            *(h8*)(dst + 56) = *(const h8*)(tp + 24);
            *(h8*)(dst + 64) = *(const h8*)(tp + 32);
        } else {
            *(h8*)(dst + 72) = *(const h8*)(tp + 40);
            *(h8*)(dst + 80) = *(const h8*)(tp + 48);
            *(h8*)(dst + 88) = *(const h8*)(tp + 56);
        }
        // B: 128 rows x 96 Och
        int row2 = t >> 1, half = t & 1;
        const _Float16* src = Och + (size_t)(n0 + row2) * 96 + half * 48;
        _Float16* bdst = Bs + row2 * 104 + half * 48;
        #pragma unroll
        for (int q = 0; q < 6; ++q) *(h8*)(bdst + q * 8) = *(const h8*)(src + q * 8);
    }
    const int wid = t >> 6, lane = t & 63;
    const int wvr = wid >> 1, wvc = wid & 1;   // 2 m-waves x 2 n-waves
    const int lr = lane & 15, lg = lane >> 4;
    float bias[4];
    #pragma unroll
    for (int nt = 0; nt < 4; ++nt) bias[nt] = cst[n0 + wvc*64 + nt*16 + lr];
    __syncthreads();

    f4 acc[2][4];
    #pragma unroll
    for (int mt = 0; mt < 2; ++mt)
        #pragma unroll
        for (int nt = 0; nt < 4; ++nt) acc[mt][nt] = f4{0.f,0.f,0.f,0.f};

    #pragma unroll
    for (int ks = 0; ks < 3; ++ks) {
        h8 av[2], bv[4];
        #pragma unroll
        for (int mt = 0; mt < 2; ++mt)
            av[mt] = *(const h8*)&As[(wvr*32 + mt*16 + lr) * 104 + ks*32 + lg*8];
        #pragma unroll
        for (int nt = 0; nt < 4; ++nt)
            bv[nt] = *(const h8*)&Bs[(wvc*64 + nt*16 + lr) * 104 + ks*32 + lg*8];
        #pragma unroll
        for (int mt = 0; mt < 2; ++mt)
            #pragma unroll
            for (int nt = 0; nt < 4; ++nt)
                acc[mt][nt] = __builtin_amdgcn_mfma_f32_16x16x32_f16(av[mt], bv[nt], acc[mt][nt], 0, 0, 0);
    }
    #pragma unroll
    for (int mt = 0; mt < 2; ++mt)
        #pragma unroll
        for (int nt = 0; nt < 4; ++nt)
            #pragma unroll
            for (int i = 0; i < 4; ++i)
                Y[(size_t)(m0 + wvr*32 + mt*16 + lg*4 + i) * 1024 + n0 + wvc*64 + nt*16 + lr]
                    = acc[mt][nt][i] + bias[nt];
}

extern "C" void kernel_launch(void* const* d_in, const int* in_sizes, int n_in,
                              void* d_out, int out_size, void* d_ws, size_t ws_size,
                              hipStream_t stream) {
    const float* X   = (const float*)d_in[0];
    const float* cst = (const float*)d_in[1];
    const float* O0  = (const float*)d_in[2];
    const float* I0  = (const float*)d_in[3];
    const float* G0  = (const float*)d_in[4];
    const float* O1  = (const float*)d_in[5];
    const float* I1  = (const float*)d_in[6];
    const float* G1  = (const float*)d_in[7];
    const float* O2  = (const float*)d_in[8];
    const float* I2  = (const float*)d_in[9];
    const float* G2  = (const float*)d_in[10];
    unsigned char* ws = (unsigned char*)d_ws;
    _Float16* Zh  = (_Float16*)(ws + ZH_OFF);
    _Float16* Th  = (_Float16*)(ws + TH_OFF);
    _Float16* Oh  = (_Float16*)(ws + OCH_OFF);
    _Float16* G2h = (_Float16*)(ws + G2H_OFF);
    float* Y = (float*)d_out;

    prep_gemmx<<<896, 512, 0, stream>>>(X, I0, I1, I2, O0, O1, O2, G0, G2, Oh, G2h, Zh);
    kron_fused<<<544, 256, 0, stream>>>(Zh, G2h, G1, Th);
    gemm_y_mfma<<<dim3(8, 64), 256, 0, stream>>>(Zh, Th, Oh, cst, Y);
}